// Round 7
// baseline (182.082 us; speedup 1.0000x reference)
//
#include <hip/hip_runtime.h>
#include <math.h>

// QueryEmb: B=4,L=512,D=512,V=32000, 4 segments of 8000, TEMP=sqrt(512).
// Equivalences: (1) masked softmax == softmax over token's own segment only;
// (2) |scores|<=~0.35 -> exp() safe without max-subtraction -> plain-sum
//     denoms and trivially split-K PV.
// R17: generation-halving. Per-block time (~18us) was invariant across all
// schedule variants; kernel time ~= ceil(live/resident) * T_block. So cut
// block count 2x with M=256 tiles: M=256 x N=128, BK=64, dbuf 48KB LDS,
// acc[8][4] (~210 VGPR -> 8 waves/CU, 2 blk/CU — same waves/CU as R16).
// k_qk: 32 c-tiles x ~18 tt ~= 600 live (~1.1 gen, was 2.2); k_pv: 8z x
// 2dt x ~18tt = 288 live (ONE generation, was ~1.2). Per phase: 64 MFMA vs
// 24 ds_read (density up). Epilogue (R16's coalesced form) scaled to
// 256-row P-tile: 32KB LDS stage, 8-pass coalesced write with tail guard;
// dpart now 64 rows. k_conv/k_qb unchanged.

constexpr int Dm   = 512;
constexpr int SEG  = 8000;
constexpr int PSTR = 8064;            // P row stride (63*128), pad rows zeroed
constexpr int NTOK = 2048;
constexpr int TIL  = 128;             // slot tile
constexpr int MAXTILES = 20;          // 2048/128 + 4 pad
constexpr int MAXSLOTS = MAXTILES * TIL;   // 2560

// ws layout (bytes)
constexpr size_t WS_META  = 8192;                                // 8 int
constexpr size_t WS_PERM  = 8448;                                // 2560 int
constexpr size_t WS_IPERM = 20480;                               // 2048 int
constexpr size_t WS_QB8   = 32768;                               // fp8 [2560][512]
constexpr size_t WS_EB8   = WS_QB8 + (size_t)MAXSLOTS * Dm;      // fp8 [32000][512]
constexpr size_t WS_OACC  = WS_EB8 + (size_t)32000 * Dm;         // bf16 [8][2560][512]
constexpr size_t WS_ET8   = WS_OACC + (size_t)8 * Dm * MAXSLOTS * 2;  // fp8 [512][32000]
constexpr size_t WS_P8    = WS_ET8 + (size_t)Dm * 32000;         // fp8 [2560][8064]
constexpr size_t WS_DPART = WS_P8 + (size_t)MAXSLOTS * PSTR;     // f32 [64][2560]
// total ~77 MB (< proven 104 MB)

typedef __attribute__((ext_vector_type(4))) float f32x4;
typedef __attribute__((ext_vector_type(4))) unsigned int u32x4;
#define LDSP __attribute__((address_space(3)))
typedef LDSP unsigned char lds_u8;
typedef LDSP u32x4 lds_v4;
typedef LDSP int lds_i32;

static __device__ __forceinline__ ushort f2bf(float f) {
    union { float f; unsigned u; } v; v.f = f;
    unsigned r = v.u + 0x7FFF + ((v.u >> 16) & 1);   // RNE
    return (ushort)(r >> 16);
}
static __device__ __forceinline__ float bf2f(ushort u) {
    union { unsigned u; float f; } v; v.u = ((unsigned)u) << 16;
    return v.f;
}
// pack 4 floats -> 4 OCP fp8 e4m3 bytes (byte0 = a .. byte3 = d)
static __device__ __forceinline__ int pack_fp8x4(float a, float b, float c, float d) {
    int r = __builtin_amdgcn_cvt_pk_fp8_f32(a, b, 0, false);
    r = __builtin_amdgcn_cvt_pk_fp8_f32(c, d, r, true);
    return r;
}

#define WAIT0 asm volatile("s_waitcnt vmcnt(0)" ::: "memory")
#define LGKM0 asm volatile("s_waitcnt lgkmcnt(0)" ::: "memory")
#define BARX  { __builtin_amdgcn_s_barrier(); __builtin_amdgcn_sched_barrier(0); }

// compute one M=256/N=128/BK=64 tile from (CA,CB): 2 k-chunks, 32 MFMA each
#define CSTEP8(CA, CB)                                                         \
    _Pragma("unroll")                                                          \
    for (int ks = 0; ks < 2; ++ks) {                                           \
        const int cg = ks*2 + (quad >> 1), ho = (quad & 1) * 8;                \
        long A[8], B[4];                                                       \
        _Pragma("unroll")                                                      \
        for (int m = 0; m < 8; ++m) {                                          \
            const int row = rh*128 + m*16 + l15;                               \
            A[m] = *(const LDSP long*)((CA) + (row*4 + (cg ^ (row & 3)))*16 + ho); \
        }                                                                      \
        _Pragma("unroll")                                                      \
        for (int n = 0; n < 4; ++n) {                                          \
            const int row = th*64 + n*16 + l15;                                \
            B[n] = *(const LDSP long*)((CB) + (row*4 + (cg ^ (row & 3)))*16 + ho); \
        }                                                                      \
        __builtin_amdgcn_s_setprio(1);                                         \
        _Pragma("unroll")                                                      \
        for (int m = 0; m < 8; ++m)                                            \
            _Pragma("unroll")                                                  \
            for (int n = 0; n < 4; ++n)                                        \
                acc[m][n] = __builtin_amdgcn_mfma_f32_16x16x32_fp8_fp8(A[m], B[n], acc[m][n], 0, 0, 0); \
        __builtin_amdgcn_s_setprio(0);                                         \
    }

// pipeline step: issue 6 loads (4 A + 2 B granules) for k-step T, compute
// (CA,CB), then wait + ds_write into (NA,NB), one barrier.
#define PSTEP8(CA, CB, NA, NB, T)                                              \
    {                                                                          \
        u32x4 sa0 = *(const u32x4*)(srcA[0] + (size_t)(T)*64);                 \
        u32x4 sa1 = *(const u32x4*)(srcA[1] + (size_t)(T)*64);                 \
        u32x4 sa2 = *(const u32x4*)(srcA[2] + (size_t)(T)*64);                 \
        u32x4 sa3 = *(const u32x4*)(srcA[3] + (size_t)(T)*64);                 \
        u32x4 sb0 = *(const u32x4*)(srcB[0] + (size_t)(T)*64);                 \
        u32x4 sb1 = *(const u32x4*)(srcB[1] + (size_t)(T)*64);                 \
        CSTEP8(CA, CB)                                                         \
        WAIT0;                                                                 \
        *(lds_v4*)((NA) + dstA[0]) = sa0;                                      \
        *(lds_v4*)((NA) + dstA[1]) = sa1;                                      \
        *(lds_v4*)((NA) + dstA[2]) = sa2;                                      \
        *(lds_v4*)((NA) + dstA[3]) = sa3;                                      \
        *(lds_v4*)((NB) + dstB[0]) = sb0;                                      \
        *(lds_v4*)((NB) + dstB[1]) = sb1;                                      \
        LGKM0; BARX;                                                           \
    }

#define PROLOG8(DA, DB)                                                        \
    {                                                                          \
        u32x4 sa0 = *(const u32x4*)(srcA[0]);                                  \
        u32x4 sa1 = *(const u32x4*)(srcA[1]);                                  \
        u32x4 sa2 = *(const u32x4*)(srcA[2]);                                  \
        u32x4 sa3 = *(const u32x4*)(srcA[3]);                                  \
        u32x4 sb0 = *(const u32x4*)(srcB[0]);                                  \
        u32x4 sb1 = *(const u32x4*)(srcB[1]);                                  \
        WAIT0;                                                                 \
        *(lds_v4*)((DA) + dstA[0]) = sa0;                                      \
        *(lds_v4*)((DA) + dstA[1]) = sa1;                                      \
        *(lds_v4*)((DA) + dstA[2]) = sa2;                                      \
        *(lds_v4*)((DA) + dstA[3]) = sa3;                                      \
        *(lds_v4*)((DB) + dstB[0]) = sb0;                                      \
        *(lds_v4*)((DB) + dstB[1]) = sb1;                                      \
        LGKM0; BARX;                                                           \
    }

// ---- K2(+K1): emb fp32 -> EB8 fp8 + ET8 fp8 transposed; last x-block: prep ----
__global__ __launch_bounds__(256)
void k_conv(const float* __restrict__ emb, unsigned char* __restrict__ EB8,
            unsigned char* __restrict__ ET8,
            const int* __restrict__ xr, int* __restrict__ meta,
            int* __restrict__ perm, int* __restrict__ iperm) {
    __shared__ unsigned char sT[64 * 8 * 16];   // 8 KB
    const int tid = threadIdx.x;
    if (blockIdx.x == 250) {                    // fused k_prep (1 block)
        if (blockIdx.y != 0) return;
        __shared__ int cnt[4], base[5], cur[4];
        if (tid < 4) { cnt[tid] = 0; cur[tid] = 0; }
        __syncthreads();
        for (int t = tid; t < NTOK; t += 256)
            atomicAdd(&cnt[xr[t]], 1);
        __syncthreads();
        if (tid == 0) {
            base[0] = 0;
            for (int r = 0; r < 4; ++r) base[r+1] = base[r] + ((cnt[r] + TIL - 1) / TIL) * TIL;
            for (int r = 0; r < 5; ++r) meta[r] = base[r];
        }
        __syncthreads();
        for (int s = tid; s < MAXSLOTS; s += 256) perm[s] = -1;
        __syncthreads();
        for (int t = tid; t < NTOK; t += 256) {
            int r = xr[t];
            int sl = base[r] + atomicAdd(&cur[r], 1);
            perm[sl] = t;
            iperm[t] = sl;
        }
        return;
    }
    const int r0 = blockIdx.x * 128, d0 = blockIdx.y * 64;
    {
        const int dq = tid & 15, ro = tid >> 4;     // 4-d group, 8-row group
        int p[8];
        #pragma unroll
        for (int i = 0; i < 8; ++i) {
            float4 v = *(const float4*)(emb + (size_t)(r0 + ro*8 + i) * Dm + d0 + dq*4);
            p[i] = pack_fp8x4(v.x, v.y, v.z, v.w);
            *(int*)(EB8 + (size_t)(r0 + ro*8 + i) * Dm + d0 + dq*4) = p[i];
        }
        const int gr = ro >> 1, half = ro & 1;
        #pragma unroll
        for (int j = 0; j < 4; ++j) {               // per d: pack 8 row-bytes
            const int d = dq*4 + j;
            unsigned long long t = 0;
            #pragma unroll
            for (int i = 0; i < 8; ++i)
                t |= ((unsigned long long)((p[i] >> (8*j)) & 0xff)) << (8*i);
            *(unsigned long long*)(sT + (d*8 + (gr ^ (d & 7))) * 16 + half * 8) = t;
        }
    }
    __syncthreads();
    {
        const int d = tid >> 2, rq = tid & 3;
        unsigned char* dst = ET8 + (size_t)(d0 + d) * 32000 + r0;
        #pragma unroll
        for (int b = 0; b < 2; ++b) {
            const int gr = rq * 2 + b;
            *(uint4*)(dst + gr * 16) = *(const uint4*)(sT + (d*8 + (gr ^ (d & 7))) * 16);
        }
    }
}

// ---- K2b: gather Q -> Qb8 fp8 [2560 slots][512] (pad slots zeroed) ----
__global__ __launch_bounds__(256)
void k_qb(const float* __restrict__ q, const int* __restrict__ perm,
          unsigned char* __restrict__ Qb8) {
    const int slot = blockIdx.x * 8 + (threadIdx.x >> 5);
    const int ln = threadIdx.x & 31;
    const int tok = perm[slot];
    #pragma unroll
    for (int j = 0; j < 4; ++j) {
        const int c4 = ln + j * 32;
        int p = 0;
        if (tok >= 0) {
            float4 v = ((const float4*)q)[(size_t)tok * 128 + c4];
            p = pack_fp8x4(v.x, v.y, v.z, v.w);
        }
        ((int*)(Qb8 + (size_t)slot * Dm))[c4] = p;
    }
}

// ---- K3: S^T = E.Q^T fp8, M=256 BK=64 reg-staged dbuf; LDS epilogue ----
__global__ __launch_bounds__(256, 2)
void k_qk(const unsigned char* __restrict__ EB8, const unsigned char* __restrict__ Qb8,
          const int* __restrict__ meta, float* __restrict__ dpart,
          unsigned char* __restrict__ P8) {
    __shared__ unsigned char smem[49152];       // 48 KB
    lds_u8* A0 = (lds_u8*)smem;                 // 16 KB (256 rows x 64 B)
    lds_u8* A1 = (lds_u8*)(smem + 16384);       // 16 KB
    lds_u8* B0 = (lds_u8*)(smem + 32768);       // 8 KB (128 rows x 64 B)
    lds_u8* B1 = (lds_u8*)(smem + 40960);       // 8 KB
    const int tid = threadIdx.x, lane = tid & 63, w = tid >> 6;
    const int g    = blockIdx.x & 7;              // XCD group
    const int rest = blockIdx.x >> 3;
    const int tt   = rest >> 2;                   // tt-outer: tail blocks last
    const int rt   = rest & 3;                    // 0..3
    const int c = g * 4 + rt;                     // row-tile 0..31 (256 rows each)
    const int slot0 = tt * TIL;
    const int b1 = meta[1], b2 = meta[2], b3 = meta[3], b4 = meta[4];
    if (slot0 >= b4) return;
    const int row0 = c * 256;
    const int rank = (slot0 >= b1) + (slot0 >= b2) + (slot0 >= b3);

    // staging map: A granule gg = i*256+tid (0..1023): r = gg>>2 (0..255),
    // cg = gg&3; swizzled pos = cg ^ (r&3). B: i*256+tid (0..511): r 0..127.
    const unsigned char* srcA[4]; int dstA[4];
    #pragma unroll
    for (int i = 0; i < 4; ++i) {
        const int gg = i * 256 + tid;
        const int r = gg >> 2, cg = gg & 3;
        int grow = row0 + r;
        if (grow >= SEG) grow = SEG - 1;          // clamp; outputs masked
        srcA[i] = EB8 + (size_t)rank * SEG * Dm + (size_t)grow * Dm + cg * 16;
        dstA[i] = (r * 4 + (cg ^ (r & 3))) * 16;
    }
    const unsigned char* srcB[2]; int dstB[2];
    #pragma unroll
    for (int i = 0; i < 2; ++i) {
        const int gg = i * 256 + tid;
        const int r = gg >> 2, cg = gg & 3;
        srcB[i] = Qb8 + (size_t)(slot0 + r) * Dm + cg * 16;
        dstB[i] = (r * 4 + (cg ^ (r & 3))) * 16;
    }
    const int rh = w >> 1, th = w & 1, quad = lane >> 4, l15 = lane & 15;
    const float invT = 0.04419417382415922f;   // 1/sqrt(512)

    f32x4 acc[8][4] = {};
    PROLOG8(A0, B0)                   // tile 0 resident
    PSTEP8(A0, B0, A1, B1, 1)
    PSTEP8(A1, B1, A0, B0, 2)
    PSTEP8(A0, B0, A1, B1, 3)
    PSTEP8(A1, B1, A0, B0, 4)
    PSTEP8(A0, B0, A1, B1, 5)
    PSTEP8(A1, B1, A0, B0, 6)
    PSTEP8(A0, B0, A1, B1, 7)
    CSTEP8(A1, B1)                    // tile 7
    BARX                              // all reads done; smem reusable

    // ---- epilogue: exp -> LDS P-tile (fp8, swizzled), then coalesced write.
    // pT logical [slot 128][int 64]; idx = slot*64 + ((r4i>>2)^(slot&15))*4 + (r4i&3)
    lds_i32* pT = (lds_i32*)smem;     // 32 KB
    float dsum[4] = {0.f, 0.f, 0.f, 0.f};
    #pragma unroll
    for (int m = 0; m < 8; ++m) {
        const int rloc = rh*128 + m*16 + quad*4;
        const int r4 = row0 + rloc;
        const int gi = (rloc >> 4);               // = rh*8 + m
        #pragma unroll
        for (int n = 0; n < 4; ++n) {
            const int slot_l = th*64 + n*16 + l15;
            int pv = 0;
            if (r4 < SEG) {
                float e0 = __expf(acc[m][n][0] * invT);
                float e1 = __expf(acc[m][n][1] * invT);
                float e2 = __expf(acc[m][n][2] * invT);
                float e3 = __expf(acc[m][n][3] * invT);
                pv = pack_fp8x4(e0, e1, e2, e3);
                dsum[n] += e0 + e1 + e2 + e3;
            }
            pT[slot_l * 64 + ((gi ^ (slot_l & 15)) << 2) + quad] = pv;
        }
    }
    BARX;
    // coalesced P8 write: 8 passes; 16 lanes cover one slot-row's 256 B
    #pragma unroll
    for (int p = 0; p < 8; ++p) {
        const int sr = (tid >> 4) + p * 16;        // slot row 0..127
        const int gi = tid & 15;                   // granule 0..15
        const int col = row0 + gi * 16;
        if (col < PSTR) {
            u32x4 v = *(const LDSP u32x4*)(pT + sr * 64 + ((gi ^ (sr & 15)) << 2));
            *(u32x4*)(P8 + (size_t)(slot0 + sr) * PSTR + col) = v;
        }
    }
    // race-free denom partials: [c*2+rh][slot] (rows 0..63)
    #pragma unroll
    for (int n = 0; n < 4; ++n) {
        float s = dsum[n];
        s += __shfl_xor(s, 16, 64);
        s += __shfl_xor(s, 32, 64);
        if (quad == 0)
            dpart[(size_t)(c * 2 + rh) * MAXSLOTS + slot0 + th*64 + n*16 + l15] = s;
    }
}

// ---- K4: O^T = E^T.P^T fp8, M=256 BK=64 reg-staged dbuf; Oacc[z][slot][d] ----
__global__ __launch_bounds__(256, 2)
void k_pv(const unsigned char* __restrict__ ET8, const unsigned char* __restrict__ P8,
          const int* __restrict__ meta, ushort* __restrict__ Oacc) {
    __shared__ unsigned char smem[49152];
    const int tid = threadIdx.x, lane = tid & 63, w = tid >> 6;
    const int z    = blockIdx.x & 7;              // K-split == XCD group
    const int rest = blockIdx.x >> 3;
    const int tt   = rest >> 1;                   // tt-outer: tail blocks last
    const int dt   = rest & 1;                    // d-tile 0..1 (256 d each)
    const int slot0 = tt * TIL;
    const int b1 = meta[1], b2 = meta[2], b3 = meta[3], b4 = meta[4];
    if (slot0 >= b4) return;
    const int rank = (slot0 >= b1) + (slot0 >= b2) + (slot0 >= b3);
    const int d0 = dt * 256;
    const int kstart = z * 1024;
    const int nit = (z == 7) ? 14 : 16;           // BK=64: 7*16+14 = 126 -> 8064 rows

    const unsigned char* srcA[4]; int dstA[4];
    #pragma unroll
    for (int i = 0; i < 4; ++i) {
        const int gg = i * 256 + tid;
        const int r = gg >> 2, cg = gg & 3;
        srcA[i] = ET8 + (size_t)(d0 + r) * 32000 + (size_t)rank * SEG + kstart + cg * 16;
        dstA[i] = (r * 4 + (cg ^ (r & 3))) * 16;
    }
    const unsigned char* srcB[2]; int dstB[2];
    #pragma unroll
    for (int i = 0; i < 2; ++i) {
        const int gg = i * 256 + tid;
        const int r = gg >> 2, cg = gg & 3;
        srcB[i] = P8 + (size_t)(slot0 + r) * PSTR + kstart + cg * 16;  // pad rows 0
        dstB[i] = (r * 4 + (cg ^ (r & 3))) * 16;
    }
    const int rh = w >> 1, th = w & 1, quad = lane >> 4, l15 = lane & 15;
    lds_u8* cA = (lds_u8*)smem;
    lds_u8* nA = (lds_u8*)(smem + 16384);
    lds_u8* cB = (lds_u8*)(smem + 32768);
    lds_u8* nB = (lds_u8*)(smem + 40960);

    f32x4 acc[8][4] = {};
    PROLOG8(cA, cB)
    for (int t = 1; t < nit; ++t) {
        PSTEP8(cA, cB, nA, nB, t)
        lds_u8* tp;
        tp = cA; cA = nA; nA = tp;
        tp = cB; cB = nB; nB = tp;
    }
    CSTEP8(cA, cB)

    ushort* Oz = Oacc + (size_t)z * MAXSLOTS * Dm;
    #pragma unroll
    for (int m = 0; m < 8; ++m) {
        const int d4 = d0 + rh*128 + m*16 + quad*4;
        #pragma unroll
        for (int n = 0; n < 4; ++n) {
            const int slot = slot0 + th*64 + n*16 + l15;
            unsigned long long u =
                  (unsigned long long)f2bf(acc[m][n][0])
                | ((unsigned long long)f2bf(acc[m][n][1]) << 16)
                | ((unsigned long long)f2bf(acc[m][n][2]) << 32)
                | ((unsigned long long)f2bf(acc[m][n][3]) << 48);
            *(unsigned long long*)(Oz + (size_t)slot * Dm + d4) = u;
        }
    }
}

// ---- K5: out[tok][d] = (sum_z Oacc[z][s][d]) / denom + q; denom from dpart ----
__global__ __launch_bounds__(256)
void k_final(const float* __restrict__ q, const int* __restrict__ iperm,
             const float* __restrict__ dpart, const ushort* __restrict__ Oacc,
             float* __restrict__ out) {
    const int tk = threadIdx.x >> 5;              // 8 tokens per block
    const int dl = threadIdx.x & 31;
    const int token = blockIdx.x * 8 + tk;
    const int s = iperm[token];
    float ds = 0.f;
    #pragma unroll
    for (int r = 0; r < 2; ++r) {
        const int j = dl + r * 32;                // 0..63 (row 63 is zeroed)
        ds += dpart[(size_t)j * MAXSLOTS + s];
    }
    ds += __shfl_xor(ds, 1, 64);
    ds += __shfl_xor(ds, 2, 64);
    ds += __shfl_xor(ds, 4, 64);
    ds += __shfl_xor(ds, 8, 64);
    ds += __shfl_xor(ds, 16, 64);
    const float inv = 1.0f / ds;
    const float* qrow = q + (size_t)token * Dm;
    float* orow = out + (size_t)token * Dm;
    #pragma unroll
    for (int p = 0; p < 4; ++p) {
        const int d = p * 128 + dl * 4;
        float a0 = 0.f, a1 = 0.f, a2 = 0.f, a3 = 0.f;
        #pragma unroll
        for (int z = 0; z < 8; ++z) {
            unsigned long long u = *(const unsigned long long*)
                (Oacc + ((size_t)z * MAXSLOTS + s) * Dm + d);
            a0 += bf2f((ushort)u);
            a1 += bf2f((ushort)(u >> 16));
            a2 += bf2f((ushort)(u >> 32));
            a3 += bf2f((ushort)(u >> 48));
        }
        float4 qv = *(const float4*)(qrow + d);
        float4 o;
        o.x = a0 * inv + qv.x; o.y = a1 * inv + qv.y;
        o.z = a2 * inv + qv.z; o.w = a3 * inv + qv.w;
        *(float4*)(orow + d) = o;                 // coalesced
    }
}

extern "C" void kernel_launch(void* const* d_in, const int* in_sizes, int n_in,
                              void* d_out, int out_size, void* d_ws, size_t ws_size,
                              hipStream_t stream) {
    const float* q   = (const float*)d_in[0];
    const int*   xr  = (const int*)d_in[1];
    const float* emb = (const float*)d_in[2];
    float* out = (float*)d_out;
    char* ws = (char*)d_ws;

    int*    meta         = (int*)(ws + WS_META);
    int*    perm         = (int*)(ws + WS_PERM);
    int*    iperm        = (int*)(ws + WS_IPERM);
    unsigned char* Qb8   = (unsigned char*)(ws + WS_QB8);
    unsigned char* EB8   = (unsigned char*)(ws + WS_EB8);
    ushort* Oacc         = (ushort*)(ws + WS_OACC);
    unsigned char* ET8   = (unsigned char*)(ws + WS_ET8);
    unsigned char* P8    = (unsigned char*)(ws + WS_P8);
    float*  dpart        = (float*)(ws + WS_DPART);

    k_conv<<<dim3(251, 8), 256, 0, stream>>>(emb, EB8, ET8, xr, meta, perm, iperm);
    k_qb<<<MAXSLOTS / 8, 256, 0, stream>>>(q, perm, Qb8);
    k_qk<<<8 * 4 * MAXTILES, 256, 0, stream>>>(EB8, Qb8, meta, dpart, P8);
    k_pv<<<8 * 2 * MAXTILES, 256, 0, stream>>>(ET8, P8, meta, Oacc);
    k_final<<<NTOK / 8, 256, 0, stream>>>(q, iperm, dpart, Oacc, out);
}

// Round 8
// 155.251 us; speedup vs baseline: 1.1728x; 1.1728x over previous
//
#include <hip/hip_runtime.h>
#include <math.h>

// QueryEmb: B=4,L=512,D=512,V=32000, 4 segments of 8000, TEMP=sqrt(512).
// Equivalences: (1) masked softmax == softmax over token's own segment only;
// (2) |scores|<=~0.35 -> exp() safe without max-subtraction -> plain-sum
//     denoms and trivially split-K PV.
// R18: sync-free register GEMM. Seven LDS-staged variants (schedules,
// phases, tiles, occupancies, epilogues) all pinned k_qk/k_pv at ~40us
// with MfmaUtil ~15% and all pipes ~70% idle -> the invariant was the
// global->LDS->reg round-trip + per-phase barrier lockstep. Now all GEMM
// operands live in MFMA-fragment-linear tiles (1KB = [quad4][row16][16B],
// K-granule 64): a wave's frag-pair load = ONE coalesced dwordx4 at
// lane*16. k_qk/k_pv: zero LDS, zero barriers, zero waitcnt in the K-loop;
// 3-deep pipelined loads (sched_barrier pins issue order), setprio around
// MFMA clusters. Layouts:
//   EB8t[vrb 2000][td 8][1024]   (K=d)      Qb8t[srb 160][td 8][1024]
//   ET8t[drb 32][t 504][1024]    (K=vocab)  P8t[srb 160][t 128][1024]
// P8t K padded to 8192; c==63 blocks zero tiles 126,127. Producers
// (k_conv/k_qb/k_qk epilogue) write tiled via small LDS transposes with
// coalesced 16B stores -- also kills k_conv's old ET8 scatter (64 lines
// per wave-store at 32KB stride). k_final/k_prep kept from R16.

constexpr int Dm   = 512;
constexpr int SEG  = 8000;
constexpr int NTOK = 2048;
constexpr int TIL  = 128;
constexpr int MAXTILES = 20;
constexpr int MAXSLOTS = MAXTILES * TIL;   // 2560

// ws layout (bytes)
constexpr size_t WS_META  = 8192;                                  // 8 int
constexpr size_t WS_PERM  = 8448;                                  // 2560 int
constexpr size_t WS_IPERM = 20480;                                 // 2048 int
constexpr size_t WS_QB8   = 32768;                                 // Qb8t 160*8*1024
constexpr size_t WS_EB8   = WS_QB8 + (size_t)160 * 8 * 1024;       // EB8t 2000*8*1024
constexpr size_t WS_OACC  = WS_EB8 + (size_t)2000 * 8 * 1024;      // bf16 [8][2560][512]
constexpr size_t WS_ET8   = WS_OACC + (size_t)8 * MAXSLOTS * Dm * 2;   // ET8t 32*504*1024
constexpr size_t WS_P8    = WS_ET8 + (size_t)32 * 504 * 1024;      // P8t 160*128*1024
constexpr size_t WS_DPART = WS_P8 + (size_t)160 * 128 * 1024;      // f32 [128][2560]
// total ~77.5 MB (< proven 104 MB)

typedef __attribute__((ext_vector_type(4))) float f32x4;
typedef __attribute__((ext_vector_type(2))) long l64x2;
#define LDSP __attribute__((address_space(3)))
typedef LDSP unsigned char lds_u8;
typedef LDSP int lds_i32;

static __device__ __forceinline__ ushort f2bf(float f) {
    union { float f; unsigned u; } v; v.f = f;
    unsigned r = v.u + 0x7FFF + ((v.u >> 16) & 1);   // RNE
    return (ushort)(r >> 16);
}
static __device__ __forceinline__ float bf2f(ushort u) {
    union { unsigned u; float f; } v; v.u = ((unsigned)u) << 16;
    return v.f;
}
// pack 4 floats -> 4 OCP fp8 e4m3 bytes (byte0 = a .. byte3 = d)
static __device__ __forceinline__ int pack_fp8x4(float a, float b, float c, float d) {
    int r = __builtin_amdgcn_cvt_pk_fp8_f32(a, b, 0, false);
    r = __builtin_amdgcn_cvt_pk_fp8_f32(c, d, r, true);
    return r;
}

// ---- register-GEMM pipeline macros (need locals: pA[4], pB[4], acc) ----
// load K-granule T (1KB/tile-row): 8 coalesced dwordx4; pin issue order.
#define LOADT(BUF, T)                                                          \
    { _Pragma("unroll")                                                        \
      for (int i = 0; i < 4; ++i) {                                            \
        BUF##a[i] = *(const l64x2*)(pA[i] + ((size_t)(T) << 10));              \
        BUF##b[i] = *(const l64x2*)(pB[i] + ((size_t)(T) << 10));              \
      }                                                                        \
      __builtin_amdgcn_sched_barrier(0); }

#define CONLY(BUF)                                                             \
    { __builtin_amdgcn_s_setprio(1);                                           \
      _Pragma("unroll")                                                        \
      for (int m = 0; m < 4; ++m)                                              \
        _Pragma("unroll")                                                      \
        for (int n = 0; n < 4; ++n)                                            \
            acc[m][n] = __builtin_amdgcn_mfma_f32_16x16x32_fp8_fp8(            \
                BUF##a[m][0], BUF##b[n][0], acc[m][n], 0, 0, 0);               \
      _Pragma("unroll")                                                        \
      for (int m = 0; m < 4; ++m)                                              \
        _Pragma("unroll")                                                      \
        for (int n = 0; n < 4; ++n)                                            \
            acc[m][n] = __builtin_amdgcn_mfma_f32_16x16x32_fp8_fp8(            \
                BUF##a[m][1], BUF##b[n][1], acc[m][n], 0, 0, 0);               \
      __builtin_amdgcn_s_setprio(0); }

#define STEPQ(LB, T, CB)  LOADT(LB, T) CONLY(CB)

// ---- K2(+K1): emb fp32 -> EB8t + ET8t (fragment-tiled); block 250: prep ----
__global__ __launch_bounds__(256)
void k_conv(const float* __restrict__ emb, unsigned char* __restrict__ EB8t,
            unsigned char* __restrict__ ET8t,
            const int* __restrict__ xr, int* __restrict__ meta,
            int* __restrict__ perm, int* __restrict__ iperm) {
    __shared__ unsigned char sE[8192];    // [128 rows][64 B], 8B-granule swizzle
    __shared__ unsigned char sT8[8192];   // [64 d][16 vg][8B], swizzle vg^(d&15)
    const int tid = threadIdx.x;
    if (blockIdx.x == 250) {              // fused k_prep (1 block)
        if (blockIdx.y != 0) return;
        __shared__ int cnt[4], base[5], cur[4];
        if (tid < 4) { cnt[tid] = 0; cur[tid] = 0; }
        __syncthreads();
        for (int t = tid; t < NTOK; t += 256)
            atomicAdd(&cnt[xr[t]], 1);
        __syncthreads();
        if (tid == 0) {
            base[0] = 0;
            for (int r = 0; r < 4; ++r) base[r+1] = base[r] + ((cnt[r] + TIL - 1) / TIL) * TIL;
            for (int r = 0; r < 5; ++r) meta[r] = base[r];
        }
        __syncthreads();
        for (int s = tid; s < MAXSLOTS; s += 256) perm[s] = -1;
        __syncthreads();
        for (int t = tid; t < NTOK; t += 256) {
            int r = xr[t];
            int sl = base[r] + atomicAdd(&cur[r], 1);
            perm[sl] = t;
            iperm[t] = sl;
        }
        return;
    }
    const int bx = blockIdx.x, by = blockIdx.y;
    const int r0 = bx * 128, d0 = by * 64;
    lds_u8* sEp = (lds_u8*)sE;
    lds_u8* sTp = (lds_u8*)sT8;
    {
        const int dq = tid & 15, ro = tid >> 4;     // 4-d group, 8-row group
        int p[8];
        #pragma unroll
        for (int i = 0; i < 8; ++i) {
            float4 v = *(const float4*)(emb + (size_t)(r0 + ro*8 + i) * Dm + d0 + dq*4);
            p[i] = pack_fp8x4(v.x, v.y, v.z, v.w);
            const int row = ro*8 + i;
            const int s = ((row >> 3) ^ row) & 7;
            *(lds_i32*)(sEp + row*64 + (((dq >> 1) ^ s) << 3) + (dq & 1)*4) = p[i];
        }
        #pragma unroll
        for (int j = 0; j < 4; ++j) {               // per d: 8B = 8 row-bytes
            const int d = dq*4 + j;
            unsigned long long t = 0;
            #pragma unroll
            for (int i = 0; i < 8; ++i)
                t |= ((unsigned long long)((p[i] >> (8*j)) & 0xff)) << (8*i);
            *(LDSP unsigned long long*)(sTp + d*128 + ((ro ^ (d & 15)) << 3)) = t;
        }
    }
    __syncthreads();
    // EB8t pass: 512 units of 16B, coalesced (1KB per wave-store group)
    #pragma unroll
    for (int p = 0; p < 2; ++p) {
        const int idx = p*256 + tid;
        const int r16 = idx & 15, qq = (idx >> 4) & 3, rb = idx >> 6;
        const int row = rb*16 + r16;
        const int s = ((row >> 3) ^ row) & 7;
        long lo = *(const LDSP long*)(sEp + row*64 + ((qq ^ s) << 3));
        long hi = *(const LDSP long*)(sEp + row*64 + (((qq + 4) ^ s) << 3));
        l64x2 v; v[0] = lo; v[1] = hi;
        *(l64x2*)(EB8t + ((((size_t)(bx*8 + rb)) * 8 + by) << 10) + (qq*16 + r16)*16) = v;
    }
    // ET8t pass
    #pragma unroll
    for (int p = 0; p < 2; ++p) {
        const int idx = p*256 + tid;
        const int r16 = idx & 15, qq = (idx >> 4) & 3, tv = (idx >> 6) & 1, drb = idx >> 7;
        const int d = drb*16 + r16;
        long lo = *(const LDSP long*)(sTp + d*128 + (((tv*8 + qq) ^ (d & 15)) << 3));
        long hi = *(const LDSP long*)(sTp + d*128 + (((tv*8 + 4 + qq) ^ (d & 15)) << 3));
        l64x2 v; v[0] = lo; v[1] = hi;
        *(l64x2*)(ET8t + (((size_t)(by*4 + drb) * 504 + bx*2 + tv) << 10) + (qq*16 + r16)*16) = v;
    }
}

// ---- K2b: gather Q -> Qb8t fragment-tiled (pad slots zeroed) ----
__global__ __launch_bounds__(256)
void k_qb(const float* __restrict__ q, const int* __restrict__ perm,
          unsigned char* __restrict__ Qb8t) {
    __shared__ unsigned char sQ[8192];    // [16 slots][512 B], 8B-granule swizzle
    lds_u8* sQp = (lds_u8*)sQ;
    const int tid = threadIdx.x;
    const int srb = blockIdx.x;           // 160 blocks of 16 slots
    const int r = tid >> 4, fidx = tid & 15;
    const int tok = perm[srb*16 + r];
    #pragma unroll
    for (int j = 0; j < 8; ++j) {
        const int f4 = fidx + j*16;       // float4 index 0..127
        int pv = 0;
        if (tok >= 0) {
            float4 v = ((const float4*)q)[(size_t)tok * 128 + f4];
            pv = pack_fp8x4(v.x, v.y, v.z, v.w);
        }
        *(lds_i32*)(sQp + r*512 + (((f4 >> 1) ^ (r & 7)) << 3) + (f4 & 1)*4) = pv;
    }
    __syncthreads();
    #pragma unroll
    for (int p = 0; p < 2; ++p) {
        const int idx = p*256 + tid;
        const int r16 = idx & 15, qq = (idx >> 4) & 3, td = idx >> 6;
        long lo = *(const LDSP long*)(sQp + r16*512 + (((td*8 + qq) ^ (r16 & 7)) << 3));
        long hi = *(const LDSP long*)(sQp + r16*512 + (((td*8 + 4 + qq) ^ (r16 & 7)) << 3));
        l64x2 v; v[0] = lo; v[1] = hi;
        *(l64x2*)(Qb8t + (((size_t)srb * 8 + td) << 10) + (qq*16 + r16)*16) = v;
    }
}

// ---- K3: S^T = E.Q^T fp8, sync-free register GEMM; exp -> P8t + dpart ----
__global__ __launch_bounds__(256, 2)
void k_qk(const unsigned char* __restrict__ EB8t, const unsigned char* __restrict__ Qb8t,
          const int* __restrict__ meta, float* __restrict__ dpart,
          unsigned char* __restrict__ P8t) {
    __shared__ unsigned char pT8[16384];  // epilogue transpose only
    const int tid = threadIdx.x, lane = tid & 63, w = tid >> 6;
    const int g    = blockIdx.x & 7;              // XCD group
    const int rest = blockIdx.x >> 3;
    const int tt   = rest >> 3;                   // tt-outer: tail blocks last
    const int rt   = rest & 7;
    const int c = g * 8 + rt;                     // vocab row-tile 0..63
    const int slot0 = tt * TIL;
    const int b1 = meta[1], b2 = meta[2], b3 = meta[3], b4 = meta[4];
    if (slot0 >= b4) return;
    if (c == 63) {                                // zero P8t K-pad tiles 126,127
        #pragma unroll
        for (int p = 0; p < 4; ++p) {
            const int idx = p*256 + tid;
            const int r16 = idx & 15, qq = (idx >> 4) & 3, tv = (idx >> 6) & 1, rb = idx >> 7;
            l64x2 zz = {0, 0};
            *(l64x2*)(P8t + ((((size_t)(slot0 >> 4) + rb) * 128 + 126 + tv) << 10)
                          + (qq*16 + r16)*16) = zz;
        }
        return;
    }
    const int rank = (slot0 >= b1) + (slot0 >= b2) + (slot0 >= b3);
    const int rh = w >> 1, th = w & 1, quad = lane >> 4, l15 = lane & 15;
    const int row0 = c * 128;

    const unsigned char* pA[4];
    const unsigned char* pB[4];
    #pragma unroll
    for (int m = 0; m < 4; ++m) {
        int rbl = c * 8 + rh * 4 + m;
        if (rbl > 499) rbl = 499;                 // clamp (c==62 tail); masked below
        pA[m] = EB8t + (((size_t)(rank * 500 + rbl)) << 13) + lane * 16;
        pB[m] = Qb8t + (((size_t)((slot0 >> 4) + th * 4 + m)) << 13) + lane * 16;
    }
    f32x4 acc[4][4] = {};
    l64x2 b0a[4], b0b[4], b1a[4], b1b[4], b2a[4], b2b[4];
    LOADT(b0, 0) LOADT(b1, 1)                     // depth-3 prologue
    STEPQ(b2, 2, b0)
    STEPQ(b0, 3, b1)
    STEPQ(b1, 4, b2)
    STEPQ(b2, 5, b0)
    STEPQ(b0, 6, b1)
    STEPQ(b1, 7, b2)
    CONLY(b0) CONLY(b1)                           // t=6, t=7

    // ---- epilogue: exp -> pT8 (LDS, swizzled) -> coalesced tiled P8t ----
    lds_u8* pTp = (lds_u8*)pT8;
    const float invT = 0.04419417382415922f;      // 1/sqrt(512)
    float dsum[4] = {0.f, 0.f, 0.f, 0.f};
    #pragma unroll
    for (int m = 0; m < 4; ++m) {
        const int rloc = rh*64 + m*16 + quad*4;
        const int r4 = row0 + rloc;
        const int gg = rloc >> 3;                 // 8B granule 0..15
        const int hh = (quad & 1) * 4;
        #pragma unroll
        for (int n = 0; n < 4; ++n) {
            const int sl = th*64 + n*16 + l15;
            int pv = 0;
            if (r4 < SEG) {
                float e0 = __expf(acc[m][n][0] * invT);
                float e1 = __expf(acc[m][n][1] * invT);
                float e2 = __expf(acc[m][n][2] * invT);
                float e3 = __expf(acc[m][n][3] * invT);
                pv = pack_fp8x4(e0, e1, e2, e3);
                dsum[n] += e0 + e1 + e2 + e3;
            }
            *(lds_i32*)(pTp + sl*128 + ((gg ^ (sl & 15)) << 3) + hh) = pv;
        }
    }
    __syncthreads();
    #pragma unroll
    for (int p = 0; p < 4; ++p) {                 // 1024 units of 16B, coalesced
        const int idx = p*256 + tid;
        const int r16 = idx & 15, qq = (idx >> 4) & 3, tv = (idx >> 6) & 1, rb = idx >> 7;
        const int sl = rb*16 + r16;
        const int g1 = tv*8 + qq;
        long lo = *(const LDSP long*)(pTp + sl*128 + ((g1 ^ (sl & 15)) << 3));
        long hi = *(const LDSP long*)(pTp + sl*128 + (((g1 + 4) ^ (sl & 15)) << 3));
        l64x2 v; v[0] = lo; v[1] = hi;
        *(l64x2*)(P8t + ((((size_t)(slot0 >> 4) + rb) * 128 + 2*c + tv) << 10)
                      + (qq*16 + r16)*16) = v;
    }
    // race-free denom partials [2c+rh][slot]
    #pragma unroll
    for (int n = 0; n < 4; ++n) {
        float s = dsum[n];
        s += __shfl_xor(s, 16, 64);
        s += __shfl_xor(s, 32, 64);
        if (quad == 0)
            dpart[(size_t)(c*2 + rh) * MAXSLOTS + slot0 + th*64 + n*16 + l15] = s;
    }
}

// ---- K4: O^T = E^T.P^T fp8, sync-free register GEMM; K-split z = XCD ----
__global__ __launch_bounds__(256, 2)
void k_pv(const unsigned char* __restrict__ ET8t, const unsigned char* __restrict__ P8t,
          const int* __restrict__ meta, ushort* __restrict__ Oacc) {
    const int tid = threadIdx.x, lane = tid & 63, w = tid >> 6;
    const int z    = blockIdx.x & 7;              // K-split == XCD group
    const int rest = blockIdx.x >> 3;
    const int tt   = rest >> 2;                   // tt-outer
    const int dt   = rest & 3;                    // d-tile 0..3 (128 d each)
    const int slot0 = tt * TIL;
    const int b1 = meta[1], b2 = meta[2], b3 = meta[3], b4 = meta[4];
    if (slot0 >= b4) return;
    const int rank = (slot0 >= b1) + (slot0 >= b2) + (slot0 >= b3);
    const int d0 = dt * 128;
    const int rh = w >> 1, th = w & 1, quad = lane >> 4, l15 = lane & 15;

    const unsigned char* pA[4];
    const unsigned char* pB[4];
    #pragma unroll
    for (int m = 0; m < 4; ++m) {
        pA[m] = ET8t + ((((size_t)(dt*8 + rh*4 + m)) * 504 + rank*125 + z*16) << 10) + lane*16;
        pB[m] = P8t + ((((size_t)((slot0 >> 4) + th*4 + m)) * 128 + z*16) << 10) + lane*16;
    }
    f32x4 acc[4][4] = {};
    l64x2 b0a[4], b0b[4], b1a[4], b1b[4], b2a[4], b2b[4];
    LOADT(b0, 0) LOADT(b1, 1)                     // NT = 16 uniform (K padded)
    STEPQ(b2, 2, b0)
    STEPQ(b0, 3, b1)
    STEPQ(b1, 4, b2)
    STEPQ(b2, 5, b0)
    STEPQ(b0, 6, b1)
    STEPQ(b1, 7, b2)
    STEPQ(b2, 8, b0)
    STEPQ(b0, 9, b1)
    STEPQ(b1, 10, b2)
    STEPQ(b2, 11, b0)
    STEPQ(b0, 12, b1)
    STEPQ(b1, 13, b2)
    STEPQ(b2, 14, b0)
    STEPQ(b0, 15, b1)
    CONLY(b2) CONLY(b0)                           // t=14, t=15

    ushort* Oz = Oacc + (size_t)z * MAXSLOTS * Dm;
    #pragma unroll
    for (int m = 0; m < 4; ++m) {
        const int d4 = d0 + rh*64 + m*16 + quad*4;
        #pragma unroll
        for (int n = 0; n < 4; ++n) {
            const int slot = slot0 + th*64 + n*16 + l15;
            unsigned long long u =
                  (unsigned long long)f2bf(acc[m][n][0])
                | ((unsigned long long)f2bf(acc[m][n][1]) << 16)
                | ((unsigned long long)f2bf(acc[m][n][2]) << 32)
                | ((unsigned long long)f2bf(acc[m][n][3]) << 48);
            *(unsigned long long*)(Oz + (size_t)slot * Dm + d4) = u;
        }
    }
}

// ---- K5: out[tok][d] = (sum_z Oacc[z][s][d]) / denom + q; denom from dpart ----
__global__ __launch_bounds__(256)
void k_final(const float* __restrict__ q, const int* __restrict__ iperm,
             const float* __restrict__ dpart, const ushort* __restrict__ Oacc,
             float* __restrict__ out) {
    const int tk = threadIdx.x >> 5;              // 8 tokens per block
    const int dl = threadIdx.x & 31;
    const int token = blockIdx.x * 8 + tk;
    const int s = iperm[token];
    float ds = 0.f;
    #pragma unroll
    for (int r = 0; r < 4; ++r) {
        const int j = dl + r * 32;
        if (j < 126) ds += dpart[(size_t)j * MAXSLOTS + s];
    }
    ds += __shfl_xor(ds, 1, 64);
    ds += __shfl_xor(ds, 2, 64);
    ds += __shfl_xor(ds, 4, 64);
    ds += __shfl_xor(ds, 8, 64);
    ds += __shfl_xor(ds, 16, 64);
    const float inv = 1.0f / ds;
    const float* qrow = q + (size_t)token * Dm;
    float* orow = out + (size_t)token * Dm;
    #pragma unroll
    for (int p = 0; p < 4; ++p) {
        const int d = p * 128 + dl * 4;
        float a0 = 0.f, a1 = 0.f, a2 = 0.f, a3 = 0.f;
        #pragma unroll
        for (int z = 0; z < 8; ++z) {
            unsigned long long u = *(const unsigned long long*)
                (Oacc + ((size_t)z * MAXSLOTS + s) * Dm + d);
            a0 += bf2f((ushort)u);
            a1 += bf2f((ushort)(u >> 16));
            a2 += bf2f((ushort)(u >> 32));
            a3 += bf2f((ushort)(u >> 48));
        }
        float4 qv = *(const float4*)(qrow + d);
        float4 o;
        o.x = a0 * inv + qv.x; o.y = a1 * inv + qv.y;
        o.z = a2 * inv + qv.z; o.w = a3 * inv + qv.w;
        *(float4*)(orow + d) = o;                 // coalesced
    }
}

extern "C" void kernel_launch(void* const* d_in, const int* in_sizes, int n_in,
                              void* d_out, int out_size, void* d_ws, size_t ws_size,
                              hipStream_t stream) {
    const float* q   = (const float*)d_in[0];
    const int*   xr  = (const int*)d_in[1];
    const float* emb = (const float*)d_in[2];
    float* out = (float*)d_out;
    char* ws = (char*)d_ws;

    int*    meta         = (int*)(ws + WS_META);
    int*    perm         = (int*)(ws + WS_PERM);
    int*    iperm        = (int*)(ws + WS_IPERM);
    unsigned char* Qb8t  = (unsigned char*)(ws + WS_QB8);
    unsigned char* EB8t  = (unsigned char*)(ws + WS_EB8);
    ushort* Oacc         = (ushort*)(ws + WS_OACC);
    unsigned char* ET8t  = (unsigned char*)(ws + WS_ET8);
    unsigned char* P8t   = (unsigned char*)(ws + WS_P8);
    float*  dpart        = (float*)(ws + WS_DPART);

    k_conv<<<dim3(251, 8), 256, 0, stream>>>(emb, EB8t, ET8t, xr, meta, perm, iperm);
    k_qb<<<160, 256, 0, stream>>>(q, perm, Qb8t);
    k_qk<<<8 * 8 * MAXTILES, 256, 0, stream>>>(EB8t, Qb8t, meta, dpart, P8t);
    k_pv<<<8 * 4 * MAXTILES, 256, 0, stream>>>(ET8t, P8t, meta, Oacc);
    k_final<<<NTOK / 8, 256, 0, stream>>>(q, iperm, dpart, Oacc, out);
}